// Round 7
// baseline (43.805 us; speedup 1.0000x reference)
//
#include <hip/hip_runtime.h>
#include <math.h>

#define DIMS 3
#define NPTS 320
#define HID  128
#define RANK 64
#define CH   160   // c rows per block (half of NPTS)
#define LROW 256   // LDS bytes per c row: hi 128B | lo 128B, XOR-swizzled

typedef __attribute__((ext_vector_type(8)))  short bf16x8;
typedef __attribute__((ext_vector_type(16))) float f32x16;

// round-to-nearest-even float -> bf16 bits
static __device__ __forceinline__ unsigned short f2bf_rn(float x) {
    union { float f; unsigned int u; } v; v.f = x;
    unsigned int r = v.u + 0x7fffu + ((v.u >> 16) & 1u);
    return (unsigned short)(r >> 16);
}
static __device__ __forceinline__ float bf2f(unsigned short h) {
    union { unsigned int u; float f; } v; v.u = ((unsigned int)h) << 16;
    return v.f;
}

// ---------------- Phase 1: per-dim MLP -> transposed factor tables ----------
__global__ __launch_bounds__(HID)
void mlp_kernel(const float* __restrict__ xs,
                const float* __restrict__ W0, const float* __restrict__ b0,
                const float* __restrict__ W1, const float* __restrict__ b1,
                const float* __restrict__ W2, const float* __restrict__ b2,
                const float* __restrict__ W3, const float* __restrict__ b3,
                float* __restrict__ f01t,
                unsigned short* __restrict__ f2hi,
                unsigned short* __restrict__ f2lo) {
    int blk = blockIdx.x;
    int d = blk / NPTS, n = blk % NPTS;
    int j = threadIdx.x;

    __shared__ float ha[HID];
    __shared__ float hb[HID];

    float x = xs[d * NPTS + n];

    ha[j] = tanhf(fmaf(x, W0[d * HID + j], b0[d * HID + j]));
    __syncthreads();

    {
        float acc = b1[d * HID + j];
        const float* w = W1 + d * HID * HID + j;
        #pragma unroll 16
        for (int k = 0; k < HID; ++k) acc = fmaf(ha[k], w[k * HID], acc);
        hb[j] = tanhf(acc);
    }
    __syncthreads();

    {
        float acc = b2[d * HID + j];
        const float* w = W2 + d * HID * HID + j;
        #pragma unroll 16
        for (int k = 0; k < HID; ++k) acc = fmaf(hb[k], w[k * HID], acc);
        ha[j] = tanhf(acc);
    }
    __syncthreads();

    if (j < RANK) {
        float acc = b3[d * RANK + j];
        const float* w = W3 + d * HID * RANK + j;
        #pragma unroll 16
        for (int k = 0; k < HID; ++k) acc = fmaf(ha[k], w[k * RANK], acc);

        if (d == 0) {
            f01t[n * RANK + j] = acc;                    // f0t[a][r]
        } else if (d == 1) {
            f01t[(NPTS + n) * RANK + j] = acc;           // f1t[b][r]
        } else {
            unsigned short hi = f2bf_rn(acc);
            f2hi[n * RANK + j] = hi;
            f2lo[n * RANK + j] = f2bf_rn(acc - bf2f(hi));
        }
    }
}

// ---------------- Phase 2: persistent-block CP via 32x32x16 bf16 MFMA -------
// out[a,b,c] = sum_r (f0[a,r]*f1[b,r]) * f2[c,r]
// 1024 blocks x 256 thr (4 waves), 4 blocks/CU (40 KB LDS) = 16 waves/CU.
// Block owns a c-half; waves cover (2 a-values x 2 b-subtiles of 32).
// Balanced contiguous tile partition; acc ping-pong so each ct's stores
// drain behind the next ct's compute (no per-ct vmcnt serialization).
__global__ __launch_bounds__(256)
void cp_mfma_kernel(const float* __restrict__ f01t,
                    const unsigned short* __restrict__ f2hi,
                    const unsigned short* __restrict__ f2lo,
                    float* __restrict__ out) {
    const int tx = threadIdx.x;
    const int w  = tx >> 6;
    const int aw = w >> 1;         // which of the 2 a-values
    const int bw = (w & 1) * 32;   // b sub-tile
    const int l  = tx & 63;
    const int lc = l & 31;         // A row(b) / B col(c) / D col(c)
    const int hw = l >> 5;         // half-wave -> k sub-group

    const int c0 = (blockIdx.x & 1) * CH;

    __shared__ char sB[CH * LROW];   // 40 KB

    // ---- stage c-half of f2hi/f2lo once (1280 float4 each, 5/thread) ----
    #pragma unroll
    for (int i = 0; i < 5; ++i) {
        int idx = tx + i * 256;               // 0..1279
        int row = idx >> 3;
        int g   = (idx & 7) << 4;
        int sw  = (row & 15) << 4;
        *(float4*)(&sB[row * LROW + (g ^ sw)]) =
            ((const float4*)f2hi)[c0 * 8 + idx];
        *(float4*)(&sB[row * LROW + ((128 + g) ^ sw)]) =
            ((const float4*)f2lo)[c0 * 8 + idx];
    }
    __syncthreads();

    // balanced contiguous partition of 800 tiles over 512 slots
    const int slot   = blockIdx.x >> 1;
    const int tstart = (slot * 25) >> 4;
    const int tend   = ((slot + 1) * 25) >> 4;

    for (int t = tstart; t < tend; ++t) {
        const int apair = t / 5;
        const int btile = t - apair * 5;
        const int a  = apair * 2 + aw;
        const int bb = btile * 64 + bw;

        const float* f0p = f01t + (size_t)a * RANK + hw * 8;
        const float* f1p = f01t + (size_t)(NPTS + bb + lc) * RANK + hw * 8;

        // ---- A fragments: g[j] = f0[a][k]*f1[b][k], k = ks*16 + hw*8 + j ----
        bf16x8 ahi[4], alo[4];
        #pragma unroll
        for (int ks = 0; ks < 4; ++ks) {
            const int k0 = ks * 16;
            float4 f0a = *(const float4*)(f0p + k0);
            float4 f0b = *(const float4*)(f0p + k0 + 4);
            float4 f1a = *(const float4*)(f1p + k0);
            float4 f1b = *(const float4*)(f1p + k0 + 4);

            float g[8];
            g[0] = f1a.x * f0a.x; g[1] = f1a.y * f0a.y;
            g[2] = f1a.z * f0a.z; g[3] = f1a.w * f0a.w;
            g[4] = f1b.x * f0b.x; g[5] = f1b.y * f0b.y;
            g[6] = f1b.z * f0b.z; g[7] = f1b.w * f0b.w;

            #pragma unroll
            for (int j = 0; j < 8; ++j) {
                unsigned short hi = f2bf_rn(g[j]);
                ahi[ks][j] = (short)hi;
                alo[ks][j] = (short)f2bf_rn(g[j] - bf2f(hi));
            }
        }

        float* obase = out + ((size_t)a * NPTS + bb) * NPTS + c0 + lc;

#define CP_STEP(CT, ACC)                                                       \
        {                                                                      \
            const int lr = (CT) * 32 + lc;                                     \
            const int sw2 = (lr & 15) << 4;                                    \
            const char* rowp = &sB[lr * LROW];                                 \
            _Pragma("unroll")                                                  \
            for (int j = 0; j < 16; ++j) ACC[j] = 0.0f;                        \
            _Pragma("unroll")                                                  \
            for (int ks = 0; ks < 4; ++ks) {                                   \
                const int base = ks * 32 + (hw << 4);                          \
                bf16x8 b_hi = *(const bf16x8*)(rowp + (base ^ sw2));           \
                bf16x8 b_lo = *(const bf16x8*)(rowp + ((128 + base) ^ sw2));   \
                ACC = __builtin_amdgcn_mfma_f32_32x32x16_bf16(ahi[ks], b_hi, ACC, 0, 0, 0); \
                ACC = __builtin_amdgcn_mfma_f32_32x32x16_bf16(ahi[ks], b_lo, ACC, 0, 0, 0); \
                ACC = __builtin_amdgcn_mfma_f32_32x32x16_bf16(alo[ks], b_hi, ACC, 0, 0, 0); \
            }                                                                  \
            _Pragma("unroll")                                                  \
            for (int q = 0; q < 16; ++q) {                                     \
                int row = (q & 3) + 8 * (q >> 2) + 4 * hw;                     \
                obase[(size_t)row * NPTS + (CT) * 32] = ACC[q];                \
            }                                                                  \
        }

        f32x16 accA, accB;
        CP_STEP(0, accA)
        CP_STEP(1, accB)
        CP_STEP(2, accA)
        CP_STEP(3, accB)
        CP_STEP(4, accA)
#undef CP_STEP
    }
}

extern "C" void kernel_launch(void* const* d_in, const int* in_sizes, int n_in,
                              void* d_out, int out_size, void* d_ws, size_t ws_size,
                              hipStream_t stream) {
    const float* xs = (const float*)d_in[0];
    const float* W0 = (const float*)d_in[1];
    const float* b0 = (const float*)d_in[2];
    const float* W1 = (const float*)d_in[3];
    const float* b1 = (const float*)d_in[4];
    const float* W2 = (const float*)d_in[5];
    const float* b2 = (const float*)d_in[6];
    const float* W3 = (const float*)d_in[7];
    const float* b3 = (const float*)d_in[8];

    // workspace: f01t float[2][NPTS][RANK] | f2hi ushort[NPTS][RANK] | f2lo same
    float* f01t = (float*)d_ws;
    unsigned short* f2hi = (unsigned short*)((char*)d_ws + 2 * NPTS * RANK * 4);
    unsigned short* f2lo = f2hi + NPTS * RANK;
    float* out = (float*)d_out;

    mlp_kernel<<<dim3(DIMS * NPTS), dim3(HID), 0, stream>>>(
        xs, W0, b0, W1, b1, W2, b2, W3, b3, f01t, f2hi, f2lo);

    cp_mfma_kernel<<<dim3(1024), dim3(256), 0, stream>>>(f01t, f2hi, f2lo, out);
}